// Round 7
// baseline (617.391 us; speedup 1.0000x reference)
//
#include <hip/hip_runtime.h>
#include <hip/hip_bf16.h>
#include <math.h>

typedef __bf16 bf16_t;
typedef __bf16 bf16x4 __attribute__((ext_vector_type(4)));
typedef __bf16 bf16x8 __attribute__((ext_vector_type(8)));
typedef float  f32x4  __attribute__((ext_vector_type(4)));
typedef float  f32x16 __attribute__((ext_vector_type(16)));

typedef __attribute__((address_space(1))) const void GVoid;
typedef __attribute__((address_space(3))) void LVoid;

__device__ __forceinline__ void gld16(const void* g, void* l) {
    __builtin_amdgcn_global_load_lds((GVoid*)g, (LVoid*)l, 16, 0, 0);
}

// tanh-form GELU via exp (max abs err ~3e-3 vs exact erf; threshold 0.119)
__device__ __forceinline__ float gelu_fast(float x) {
    float x2 = x * x;
    float y  = fmaf(0.044715f * x2, x, x);
    float e  = __expf(-1.5957691216057308f * y);
    return x / (1.0f + e);
}

// ---------------------------------------------------------------------------
// Batched 4x square transpose + downcast: f32 (1024x1024) -> bf16 (1024x1024)^T
// ---------------------------------------------------------------------------
struct TP4 {
    const float *s0, *s1, *s2, *s3;
    bf16_t *d0, *d1, *d2, *d3;
};
__global__ __launch_bounds__(256) void transpose4_f32_bf16(TP4 p)
{
    __shared__ bf16_t tile[64][65];
    const int z = blockIdx.z;
    const float* src = z == 0 ? p.s0 : z == 1 ? p.s1 : z == 2 ? p.s2 : p.s3;
    bf16_t*      dst = z == 0 ? p.d0 : z == 1 ? p.d1 : z == 2 ? p.d2 : p.d3;
    const int r0 = blockIdx.y * 64, c0 = blockIdx.x * 64;
    const int t = threadIdx.x, tc = t & 63, tr = t >> 6;
#pragma unroll
    for (int i = 0; i < 16; ++i) {
        int r = tr + i * 4;
        tile[r][tc] = (bf16_t)src[(size_t)(r0 + r) * 1024 + c0 + tc];
    }
    __syncthreads();
#pragma unroll
    for (int i = 0; i < 16; ++i) {
        int r = tr + i * 4;
        dst[(size_t)(c0 + r) * 1024 + r0 + tc] = tile[tc][r];
    }
}

// ---------------------------------------------------------------------------
// Tiled transpose + downcast (batched): f32 (R x C) -> bf16 (C x R) per batch.
// ---------------------------------------------------------------------------
__global__ __launch_bounds__(256) void transpose_f32_bf16(
    const float* __restrict__ in, bf16_t* __restrict__ out,
    int R, int C, size_t inBatch, size_t outBatch)
{
    __shared__ bf16_t tile[64][65];
    const float* src = in  + (size_t)blockIdx.z * inBatch;
    bf16_t*      dst = out + (size_t)blockIdx.z * outBatch;
    const int r0 = blockIdx.y * 64, c0 = blockIdx.x * 64;
    const int t = threadIdx.x, tc = t & 63, tr = t >> 6;
#pragma unroll
    for (int i = 0; i < 16; ++i) {
        int r = tr + i * 4;
        tile[r][tc] = (bf16_t)src[(size_t)(r0 + r) * C + c0 + tc];
    }
    __syncthreads();
#pragma unroll
    for (int i = 0; i < 16; ++i) {
        int r = tr + i * 4;
        dst[(size_t)(c0 + r) * R + r0 + tc] = tile[tc][r];
    }
}

// ---------------------------------------------------------------------------
// Tiled bf16 transpose (batched): per-head V (1024x64) -> (64x1024).
// ---------------------------------------------------------------------------
__global__ __launch_bounds__(256) void transpose_bf16(
    const bf16_t* __restrict__ in, bf16_t* __restrict__ out,
    int R, int C, size_t inBatch, size_t outBatch)
{
    __shared__ __align__(16) bf16_t tile[64][65];
    const bf16_t* src = in  + (size_t)blockIdx.z * inBatch;
    bf16_t*       dst = out + (size_t)blockIdx.z * outBatch;
    const int r0 = blockIdx.y * 64, c0 = blockIdx.x * 64;
    const int t = threadIdx.x, tc = t & 63, tr = t >> 6;
#pragma unroll
    for (int i = 0; i < 16; ++i) {
        int r = tr + i * 4;
        tile[r][tc] = src[(size_t)(r0 + r) * C + c0 + tc];
    }
    __syncthreads();
#pragma unroll
    for (int i = 0; i < 16; ++i) {
        int r = tr + i * 4;
        dst[(size_t)(c0 + r) * R + r0 + tc] = tile[tc][r];
    }
}

// ---------------------------------------------------------------------------
// LayerNorm rows of 1024: f32 in -> bf16 out. One 256-thread block / row.
// ---------------------------------------------------------------------------
__global__ __launch_bounds__(256) void ln_kernel(
    const float* __restrict__ x, const float* __restrict__ g,
    const float* __restrict__ b, bf16_t* __restrict__ out)
{
    const int row = blockIdx.x, t = threadIdx.x;
    const float* xr = x + (size_t)row * 1024;
    float v[4];
#pragma unroll
    for (int i = 0; i < 4; ++i) v[i] = xr[t * 4 + i];
    float s = v[0] + v[1] + v[2] + v[3];
    float s2 = v[0]*v[0] + v[1]*v[1] + v[2]*v[2] + v[3]*v[3];
#pragma unroll
    for (int o = 1; o < 64; o <<= 1) { s += __shfl_xor(s, o); s2 += __shfl_xor(s2, o); }
    __shared__ float red[8];
    if ((t & 63) == 0) { red[t >> 6] = s; red[4 + (t >> 6)] = s2; }
    __syncthreads();
    s  = red[0] + red[1] + red[2] + red[3];
    s2 = red[4] + red[5] + red[6] + red[7];
    const float mean = s * (1.f / 1024.f);
    const float var  = fmaxf(s2 * (1.f / 1024.f) - mean * mean, 0.f);
    const float rstd = rsqrtf(var + 1e-5f);
#pragma unroll
    for (int i = 0; i < 4; ++i) {
        int c = t * 4 + i;
        out[(size_t)row * 1024 + c] =
            (bf16_t)((v[i] - mean) * rstd * g[c] + b[c]);
    }
}

// ---------------------------------------------------------------------------
// GEMM via 32x32x16 MFMA: C(M,N) = A(M,K) @ Bt(N,K)^T, bf16 in, 128x128 tile,
// BK=32, 4 waves (2x2); each wave = 2x2 tiles of 32x32 (acc 2x2 f32x16).
// A/B frag: lane&31 = row, k = (lane>>5)*8 + elem (+16 per kc).
// C/D: col = lane&31, row = (reg&3) + 8*(reg>>2) + 4*(lane>>5).
// MODE 1: out_f  = acc + bias + resid_f   (resid may alias out)
// MODE 2: out_bf = gelu_fast(acc + bias)
// MODE 5: out_f += acc
// ---------------------------------------------------------------------------
template <int MODE>
__global__ __launch_bounds__(256) void gemm_bt(
    const bf16_t* __restrict__ A, const bf16_t* __restrict__ Bt,
    const float* __restrict__ bias, const float* resid_f,
    bf16_t* __restrict__ out_bf, float* out_f, int N, int K)
{
    __shared__ __align__(16) bf16_t As[128 * 32];
    __shared__ __align__(16) bf16_t Bs[128 * 32];
    const int t = threadIdx.x;
    const int wv = t >> 6, ln = t & 63;
    const int wx = wv & 1, wy = wv >> 1;
    const int l32 = ln & 31, half = ln >> 5;
    const int m0 = blockIdx.x * 128, n0 = blockIdx.y * 128;

    f32x16 acc[2][2];
#pragma unroll
    for (int i = 0; i < 2; ++i)
#pragma unroll
        for (int j = 0; j < 2; ++j)
#pragma unroll
            for (int r = 0; r < 16; ++r) acc[i][j][r] = 0.f;

    const int arow = t >> 2;
    const int acol = (t & 3) << 3;
    const bf16_t* gA = A  + (size_t)(m0 + arow) * K + acol;
    const bf16_t* gB = Bt + (size_t)(n0 + arow) * K + acol;
    char* ldsA = (char*)As + wv * 1024;
    char* ldsB = (char*)Bs + wv * 1024;

    for (int kk = 0; kk < K; kk += 32) {
        __syncthreads();
        gld16(gA + kk,                 ldsA);
        gld16(gA + (size_t)64*K + kk,  ldsA + 4096);
        gld16(gB + kk,                 ldsB);
        gld16(gB + (size_t)64*K + kk,  ldsB + 4096);
        __syncthreads();

        bf16x8 af[2][2], bfr[2][2];
        const bf16_t* Ab = As + (wy * 64 + l32) * 32 + half * 8;
        const bf16_t* Bb = Bs + (wx * 64 + l32) * 32 + half * 8;
#pragma unroll
        for (int i = 0; i < 2; ++i)
#pragma unroll
            for (int kc = 0; kc < 2; ++kc) {
                af[i][kc]  = *(const bf16x8*)(Ab + i * 1024 + kc * 16);
                bfr[i][kc] = *(const bf16x8*)(Bb + i * 1024 + kc * 16);
            }
#pragma unroll
        for (int kc = 0; kc < 2; ++kc)
#pragma unroll
            for (int i = 0; i < 2; ++i)
#pragma unroll
                for (int j = 0; j < 2; ++j)
                    acc[i][j] = __builtin_amdgcn_mfma_f32_32x32x16_bf16(
                        af[i][kc], bfr[j][kc], acc[i][j], 0, 0, 0);
    }

#pragma unroll
    for (int j = 0; j < 2; ++j) {
        const int col = n0 + wx * 64 + j * 32 + l32;
        const float bc = bias[col];
#pragma unroll
        for (int i = 0; i < 2; ++i) {
            const int rowb = m0 + wy * 64 + i * 32 + 4 * half;
#pragma unroll
            for (int r = 0; r < 16; ++r) {
                const int row = rowb + (r & 3) + 8 * (r >> 2);
                const size_t idx = (size_t)row * N + col;
                float vv = acc[i][j][r] + bc;
                if (MODE == 1) out_f[idx] = vv + resid_f[idx];
                else if (MODE == 2) out_bf[idx] = (bf16_t)gelu_fast(vv);
                else out_f[idx] += acc[i][j][r];
            }
        }
    }
}

// ---------------------------------------------------------------------------
// Fused QKV GEMM (32x32x16): A(8192x1024) @ [Wq|Wk|Wv]^T (3072x1024 Bt).
// ---------------------------------------------------------------------------
__global__ __launch_bounds__(256) void gemm_qkv(
    const bf16_t* __restrict__ A, const bf16_t* __restrict__ Bt,
    const float* __restrict__ bq, const float* __restrict__ bk,
    const float* __restrict__ bv,
    bf16_t* __restrict__ Qo, bf16_t* __restrict__ Ko, bf16_t* __restrict__ Vo,
    int K)
{
    __shared__ __align__(16) bf16_t As[128 * 32];
    __shared__ __align__(16) bf16_t Bs[128 * 32];
    const int t = threadIdx.x;
    const int wv = t >> 6, ln = t & 63;
    const int wx = wv & 1, wy = wv >> 1;
    const int l32 = ln & 31, half = ln >> 5;
    const int m0 = blockIdx.x * 128, n0 = blockIdx.y * 128;

    f32x16 acc[2][2];
#pragma unroll
    for (int i = 0; i < 2; ++i)
#pragma unroll
        for (int j = 0; j < 2; ++j)
#pragma unroll
            for (int r = 0; r < 16; ++r) acc[i][j][r] = 0.f;

    const int arow = t >> 2;
    const int acol = (t & 3) << 3;
    const bf16_t* gA = A  + (size_t)(m0 + arow) * K + acol;
    const bf16_t* gB = Bt + (size_t)(n0 + arow) * K + acol;
    char* ldsA = (char*)As + wv * 1024;
    char* ldsB = (char*)Bs + wv * 1024;

    for (int kk = 0; kk < K; kk += 32) {
        __syncthreads();
        gld16(gA + kk,                 ldsA);
        gld16(gA + (size_t)64*K + kk,  ldsA + 4096);
        gld16(gB + kk,                 ldsB);
        gld16(gB + (size_t)64*K + kk,  ldsB + 4096);
        __syncthreads();

        bf16x8 af[2][2], bfr[2][2];
        const bf16_t* Ab = As + (wy * 64 + l32) * 32 + half * 8;
        const bf16_t* Bb = Bs + (wx * 64 + l32) * 32 + half * 8;
#pragma unroll
        for (int i = 0; i < 2; ++i)
#pragma unroll
            for (int kc = 0; kc < 2; ++kc) {
                af[i][kc]  = *(const bf16x8*)(Ab + i * 1024 + kc * 16);
                bfr[i][kc] = *(const bf16x8*)(Bb + i * 1024 + kc * 16);
            }
#pragma unroll
        for (int kc = 0; kc < 2; ++kc)
#pragma unroll
            for (int i = 0; i < 2; ++i)
#pragma unroll
                for (int j = 0; j < 2; ++j)
                    acc[i][j] = __builtin_amdgcn_mfma_f32_32x32x16_bf16(
                        af[i][kc], bfr[j][kc], acc[i][j], 0, 0, 0);
    }

    const int which = n0 >> 10;                         // block-uniform
    const float* bias = which == 0 ? bq : (which == 1 ? bk : bv);
    bf16_t* outp      = which == 0 ? Qo : (which == 1 ? Ko : Vo);
    const int nloc = n0 & 1023;
#pragma unroll
    for (int j = 0; j < 2; ++j) {
        const int col = nloc + wx * 64 + j * 32 + l32;
        const float bc = bias[col];
#pragma unroll
        for (int i = 0; i < 2; ++i) {
            const int rowb = m0 + wy * 64 + i * 32 + 4 * half;
#pragma unroll
            for (int r = 0; r < 16; ++r) {
                const int row = rowb + (r & 3) + 8 * (r >> 2);
                outp[(size_t)row * 1024 + col] = (bf16_t)(acc[i][j][r] + bc);
            }
        }
    }
}

// ---------------------------------------------------------------------------
// Flash attention, conflict-free LDS (K stride 72, V/P stride 136).
// Computes S^T = K.Q^T so P leaves MFMA with 4 consecutive k per lane.
// (verified in R5/R6 — unchanged)
// ---------------------------------------------------------------------------
__global__ __launch_bounds__(256, 2) void attn_kernel(
    const bf16_t* __restrict__ Q, const bf16_t* __restrict__ K,
    const bf16_t* __restrict__ Vt, bf16_t* __restrict__ O)
{
    __shared__ __align__(16) bf16_t smem[26112];
    bf16_t* Vs = smem;             // 64*136
    bf16_t* Ks = smem + 8704;      // 128*72
    bf16_t* Ps = smem + 8704;      // 128*136 (overlays Ks)

    const int t = threadIdx.x;
    const int wv = t >> 6, ln = t & 63;
    const int l16 = ln & 15, quad = ln >> 4;
    const int qt = blockIdx.x, bh = blockIdx.y;
    const size_t hb = (size_t)bh << 16;

    bf16x8 qf[2][2];
#pragma unroll
    for (int rt = 0; rt < 2; ++rt)
#pragma unroll
        for (int ks = 0; ks < 2; ++ks)
            qf[rt][ks] = *(const bf16x8*)(Q + hb +
                (size_t)(qt*128 + wv*32 + rt*16 + l16) * 64 + ks*32 + quad*8);

    float m_run[2] = {-INFINITY, -INFINITY};
    float l_run[2] = {0.f, 0.f};
    f32x4 acc_o[2][4];
#pragma unroll
    for (int rt = 0; rt < 2; ++rt)
#pragma unroll
        for (int dt = 0; dt < 4; ++dt) acc_o[rt][dt] = f32x4{0.f, 0.f, 0.f, 0.f};

    const int krow = t >> 3, kcol = (t & 7) << 3;
    const int vrow = t >> 4, vcol = (t & 15) << 3;
    const float sc = 0.125f;

    for (int j = 0; j < 8; ++j) {
        bf16x8 kg[4], vg[4];
#pragma unroll
        for (int i = 0; i < 4; ++i) {
            kg[i] = *(const bf16x8*)(K  + hb + (size_t)(j*128 + i*32 + krow)*64 + kcol);
            vg[i] = *(const bf16x8*)(Vt + hb + (size_t)(i*16 + vrow)*1024 + j*128 + vcol);
        }
        __syncthreads();
#pragma unroll
        for (int i = 0; i < 4; ++i) {
            *(bf16x8*)(Ks + (i*32 + krow)*72 + kcol)  = kg[i];
            *(bf16x8*)(Vs + (i*16 + vrow)*136 + vcol) = vg[i];
        }
        __syncthreads();

        f32x4 accs[8][2];
#pragma unroll
        for (int nt = 0; nt < 8; ++nt)
#pragma unroll
            for (int rt = 0; rt < 2; ++rt) accs[nt][rt] = f32x4{0.f, 0.f, 0.f, 0.f};
#pragma unroll
        for (int ks = 0; ks < 2; ++ks)
#pragma unroll
            for (int nt = 0; nt < 8; ++nt) {
                bf16x8 kf = *(const bf16x8*)(Ks + (nt*16 + l16)*72 + ks*32 + quad*8);
#pragma unroll
                for (int rt = 0; rt < 2; ++rt)
                    accs[nt][rt] = __builtin_amdgcn_mfma_f32_16x16x32_bf16(
                        kf, qf[rt][ks], accs[nt][rt], 0, 0, 0);
            }

#pragma unroll
        for (int rt = 0; rt < 2; ++rt) {
            float mx = -INFINITY;
#pragma unroll
            for (int nt = 0; nt < 8; ++nt)
#pragma unroll
                for (int r = 0; r < 4; ++r) mx = fmaxf(mx, accs[nt][rt][r]);
            mx *= sc;
            mx = fmaxf(mx, __shfl_xor(mx, 16));
            mx = fmaxf(mx, __shfl_xor(mx, 32));
            const float mnew  = fmaxf(m_run[rt], mx);
            const float alpha = __expf(m_run[rt] - mnew);
            m_run[rt] = mnew;
            float rs = 0.f;
#pragma unroll
            for (int nt = 0; nt < 8; ++nt)
#pragma unroll
                for (int r = 0; r < 4; ++r) {
                    float p = __expf(accs[nt][rt][r] * sc - mnew);
                    accs[nt][rt][r] = p;
                    rs += p;
                }
            rs += __shfl_xor(rs, 16);
            rs += __shfl_xor(rs, 32);
            l_run[rt] = l_run[rt] * alpha + rs;
#pragma unroll
            for (int r = 0; r < 4; ++r) {
                const float af = __shfl(alpha, quad*4 + r, 16);
#pragma unroll
                for (int dt = 0; dt < 4; ++dt) acc_o[rt][dt][r] *= af;
            }
        }

        __syncthreads();
#pragma unroll
        for (int rt = 0; rt < 2; ++rt) {
            const int mrow = wv*32 + rt*16 + l16;
#pragma unroll
            for (int nt = 0; nt < 8; ++nt) {
                bf16x4 pk;
#pragma unroll
                for (int r = 0; r < 4; ++r) pk[r] = (bf16_t)accs[nt][rt][r];
                *(bf16x4*)(Ps + mrow*136 + nt*16 + quad*4) = pk;
            }
        }
#pragma unroll
        for (int ks = 0; ks < 4; ++ks) {
            bf16x8 ap[2];
#pragma unroll
            for (int rt = 0; rt < 2; ++rt)
                ap[rt] = *(const bf16x8*)(Ps + (wv*32 + rt*16 + l16)*136 + ks*32 + quad*8);
#pragma unroll
            for (int dt = 0; dt < 4; ++dt) {
                bf16x8 bvv = *(const bf16x8*)(Vs + (dt*16 + l16)*136 + ks*32 + quad*8);
#pragma unroll
                for (int rt = 0; rt < 2; ++rt)
                    acc_o[rt][dt] = __builtin_amdgcn_mfma_f32_16x16x32_bf16(
                        ap[rt], bvv, acc_o[rt][dt], 0, 0, 0);
            }
        }
    }

    const int b = bh >> 4, h = bh & 15;
#pragma unroll
    for (int rt = 0; rt < 2; ++rt) {
#pragma unroll
        for (int r = 0; r < 4; ++r) {
            const float inv = 1.f / __shfl(l_run[rt], quad*4 + r, 16);
            const int m = qt*128 + wv*32 + rt*16 + quad*4 + r;
#pragma unroll
            for (int dt = 0; dt < 4; ++dt) {
                const int d = dt*16 + l16;
                O[((size_t)b*1024 + m)*1024 + h*64 + d] =
                    (bf16_t)(acc_o[rt][dt][r] * inv);
            }
        }
    }
}

// ---------------------------------------------------------------------------
extern "C" void kernel_launch(void* const* d_in, const int* in_sizes, int n_in,
                              void* d_out, int out_size, void* d_ws, size_t ws_size,
                              hipStream_t stream)
{
    (void)in_sizes; (void)n_in;
    const size_t MB = 1ull << 20;
    if (ws_size < 64 * MB) {
        hipMemsetAsync(d_out, 0, (size_t)out_size * sizeof(float), stream);
        return;
    }

    const float* x  = (const float*)d_in[0];
    const float* g1 = (const float*)d_in[1];
    const float* b1 = (const float*)d_in[2];
    const float* Wq = (const float*)d_in[3];
    const float* bq = (const float*)d_in[4];
    const float* Wk = (const float*)d_in[5];
    const float* bk = (const float*)d_in[6];
    const float* Wv = (const float*)d_in[7];
    const float* bv = (const float*)d_in[8];
    const float* Wp = (const float*)d_in[9];
    const float* bp = (const float*)d_in[10];
    const float* g2 = (const float*)d_in[11];
    const float* b2 = (const float*)d_in[12];
    const float* W1 = (const float*)d_in[13];
    const float* c1 = (const float*)d_in[14];
    const float* W2 = (const float*)d_in[15];
    const float* c2 = (const float*)d_in[16];

    // Workspace (64 MB):
    //   0-16  (S0): Kb            -> hid[0:16MB]
    //   16-32 (S1): Vb -> Ob      -> hid[16:32MB]   (hid = 8192x2048 bf16)
    //   32-48 (S2): h1 -> Vt -> h2
    //   48-54     : WqT|WkT|WvT (QKV fused Bt)  -> W2T (8 MB @48-56, after proj)
    //   54-56     : WpT
    //   56-64     : W1T (4096x1024)
    //   d_out (32 MB f32): Qb bf16 -> x2 f32 -> final out (FC2 RMW in place)
    char* ws = (char*)d_ws;
    bf16_t* Kb  = (bf16_t*)(ws);
    bf16_t* Vb  = (bf16_t*)(ws + 16 * MB);
    bf16_t* Cs  = (bf16_t*)(ws + 32 * MB);
    bf16_t* WqT = (bf16_t*)(ws + 48 * MB);
    bf16_t* WpT = (bf16_t*)(ws + 54 * MB);
    bf16_t* W1T = (bf16_t*)(ws + 56 * MB);
    bf16_t* W2T = (bf16_t*)(ws + 48 * MB);   // after WqkvT/WpT dead
    bf16_t* Qb  = (bf16_t*)d_out;
    bf16_t* Ob  = Vb;
    bf16_t* hid = Kb;                        // 32 MB spanning S0+S1
    bf16_t* h2  = Cs;
    float*  x2  = (float*)d_out;
    float*  outf = (float*)d_out;

    const dim3 blk(256);

    // batched weight transposes (f32 -> bf16, (N,K)); Wq/Wk/Wv contiguous
    TP4 tp{Wq, Wk, Wv, Wp,
           WqT, WqT + 1024*1024, WqT + 2*1024*1024, WpT};
    transpose4_f32_bf16<<<dim3(16, 16, 4), blk, 0, stream>>>(tp);
    transpose_f32_bf16<<<dim3(64, 16, 1), blk, 0, stream>>>(W1, W1T, 1024, 4096, 0, 0);

    // LN1: x -> h1 (Cs)
    ln_kernel<<<8192, blk, 0, stream>>>(x, g1, b1, Cs);

    // fused QKV: 1536 blocks
    gemm_qkv<<<dim3(64, 24), blk, 0, stream>>>(Cs, WqT, bq, bk, bv, Qb, Kb, Vb, 1024);

    // per-head V transpose: V(S1) -> Vt(S2)
    transpose_bf16<<<dim3(1, 16, 128), blk, 0, stream>>>(Vb, Cs, 1024, 64, 65536, 65536);

    // flash attention: Q(d_out), K(S0), Vt(S2) -> Ob(S1)
    attn_kernel<<<dim3(8, 128), blk, 0, stream>>>(Qb, Kb, Cs, Ob);

    // proj + residual: Ob @ Wp + bp + x -> x2 (f32, d_out)
    gemm_bt<1><<<dim3(64, 8), blk, 0, stream>>>(Ob, WpT, bp, x, nullptr, x2, 1024, 1024);

    // W2 -> 2 K-chunks (1024 x 2048 each), into dead weights arena @48-56
    transpose_f32_bf16<<<dim3(16, 32, 2), blk, 0, stream>>>(
        W2, W2T, 2048, 1024, 2048*1024, 2048*1024);

    // LN2: x2 -> h2 (Cs)
    ln_kernel<<<8192, blk, 0, stream>>>(x2, g2, b2, h2);

    // MLP: 2 K-chunks of 2048; hid = 8192x2048 bf16 (32 MB @ S0+S1)
    for (int c = 0; c < 2; ++c) {
        gemm_bt<2><<<dim3(64, 16), blk, 0, stream>>>(
            h2, W1T + (size_t)c * 2048 * 1024, c1 + c * 2048, nullptr,
            hid, nullptr, 2048, 1024);
        if (c == 0)
            gemm_bt<1><<<dim3(64, 8), blk, 0, stream>>>(
                hid, W2T, c2, outf, nullptr, outf, 1024, 2048);
        else
            gemm_bt<5><<<dim3(64, 8), blk, 0, stream>>>(
                hid, W2T + (size_t)2048 * 1024, c2, nullptr, nullptr,
                outf, 1024, 2048);
    }
}